// Round 3
// baseline (97.178 us; speedup 1.0000x reference)
//
#include <hip/hip_runtime.h>

// Problem: out[b,s,r] = | prod_w cos(0.5*(x[b,s,w] - refs[r,w])) |
// B=64, S=32768, R=4, W=4. x:(B,S,4) f32, refs:(4,4) f32, out:(B,S,4) f32.
// Memory-bound streaming op: 33.5 MB in + 33.5 MB out -> ~10.6 us @ 6.3 TB/s.
// Round-3 fix: __builtin_nontemporal_* requires native vector types, not
// HIP_vector_type — use clang ext_vector_type(4) float for the 16B accesses.

#define QKE_R 4
#define QKE_W 4

typedef float f32x4 __attribute__((ext_vector_type(4)));

__global__ __launch_bounds__(256) void
QuantumKernelEmbedding_kernel(const float* __restrict__ x,
                              const float* __restrict__ refs,
                              float* __restrict__ out,
                              int npts) {
    // Half-scaled refs -> registers (uniform address, compile-time indices).
    float rf[QKE_R][QKE_W];
#pragma unroll
    for (int r = 0; r < QKE_R; ++r)
#pragma unroll
        for (int w = 0; w < QKE_W; ++w)
            rf[r][w] = 0.5f * refs[r * QKE_W + w];

    const f32x4* __restrict__ x4 = reinterpret_cast<const f32x4*>(x);
    f32x4* __restrict__ o4 = reinterpret_cast<f32x4*>(out);

    int i0 = 2 * (blockIdx.x * blockDim.x + threadIdx.x);  // 2 points/thread

#pragma unroll
    for (int k = 0; k < 2; ++k) {
        int i = i0 + k;
        if (i >= npts) return;
        f32x4 xv = __builtin_nontemporal_load(&x4[i]);  // 16B coalesced, nt
        float hx[QKE_W] = {0.5f * xv.x, 0.5f * xv.y, 0.5f * xv.z, 0.5f * xv.w};

        float res[QKE_R];
#pragma unroll
        for (int r = 0; r < QKE_R; ++r) {
            float p = 1.0f;
#pragma unroll
            for (int w = 0; w < QKE_W; ++w)
                p *= __cosf(hx[w] - rf[r][w]);  // native v_cos_f32 path
            res[r] = fabsf(p);
        }
        // r is innermost out dim -> 16B coalesced nt store
        f32x4 ov;
        ov.x = res[0]; ov.y = res[1]; ov.z = res[2]; ov.w = res[3];
        __builtin_nontemporal_store(ov, &o4[i]);
    }
}

extern "C" void kernel_launch(void* const* d_in, const int* in_sizes, int n_in,
                              void* d_out, int out_size, void* d_ws, size_t ws_size,
                              hipStream_t stream) {
    const float* x = (const float*)d_in[0];     // (B,S,W) f32
    const float* refs = (const float*)d_in[1];  // (R,W) f32
    float* out = (float*)d_out;                 // (B,S,R) f32

    const int npts = in_sizes[0] / QKE_W;  // B*S = 2,097,152

    const int block = 256;
    const int pts_per_block = 2 * block;  // 2 points/thread
    const int grid = (npts + pts_per_block - 1) / pts_per_block;  // 4096

    QuantumKernelEmbedding_kernel<<<grid, block, 0, stream>>>(x, refs, out, npts);
}

// Round 4
// 81.290 us; speedup vs baseline: 1.1954x; 1.1954x over previous
//
#include <hip/hip_runtime.h>

// Problem: out[b,s,r] = | prod_w cos(0.5*(x[b,s,w] - refs[r,w])) |
// B=64, S=32768, R=4, W=4. x:(B,S,4) f32, refs:(4,4) f32, out:(B,S,4) f32.
// Memory-bound streaming op: 33.5 MB in + 33.5 MB out -> ~10.6 us @ 6.3 TB/s.
// Round-4: revert round-3's stride-2 regression. Exact grid, 1 point/thread,
// fully contiguous 16B/lane load+store. nt on store only (write-once data;
// avoid L2 write-allocate). Plain load (L1 allocate harmless, keeps lines
// shared within the wave's single access).

#define QKE_R 4
#define QKE_W 4

typedef float f32x4 __attribute__((ext_vector_type(4)));

__global__ __launch_bounds__(256) void
QuantumKernelEmbedding_kernel(const float* __restrict__ x,
                              const float* __restrict__ refs,
                              float* __restrict__ out,
                              int npts) {
    // Half-scaled refs -> registers (uniform address, compile-time indices).
    float rf[QKE_R][QKE_W];
#pragma unroll
    for (int r = 0; r < QKE_R; ++r)
#pragma unroll
        for (int w = 0; w < QKE_W; ++w)
            rf[r][w] = 0.5f * refs[r * QKE_W + w];

    const f32x4* __restrict__ x4 = reinterpret_cast<const f32x4*>(x);
    f32x4* __restrict__ o4 = reinterpret_cast<f32x4*>(out);

    int i = blockIdx.x * blockDim.x + threadIdx.x;  // 1 point/thread, contiguous
    if (i >= npts) return;

    f32x4 xv = x4[i];  // 16B coalesced load (lane i -> byte 16*i)
    float hx[QKE_W] = {0.5f * xv.x, 0.5f * xv.y, 0.5f * xv.z, 0.5f * xv.w};

    float res[QKE_R];
#pragma unroll
    for (int r = 0; r < QKE_R; ++r) {
        float p = 1.0f;
#pragma unroll
        for (int w = 0; w < QKE_W; ++w)
            p *= __cosf(hx[w] - rf[r][w]);  // native v_cos_f32 path
        res[r] = fabsf(p);
    }
    // r is innermost out dim -> 16B coalesced nt store (no L2 write-allocate)
    f32x4 ov;
    ov.x = res[0]; ov.y = res[1]; ov.z = res[2]; ov.w = res[3];
    __builtin_nontemporal_store(ov, &o4[i]);
}

extern "C" void kernel_launch(void* const* d_in, const int* in_sizes, int n_in,
                              void* d_out, int out_size, void* d_ws, size_t ws_size,
                              hipStream_t stream) {
    const float* x = (const float*)d_in[0];     // (B,S,W) f32
    const float* refs = (const float*)d_in[1];  // (R,W) f32
    float* out = (float*)d_out;                 // (B,S,R) f32

    const int npts = in_sizes[0] / QKE_W;  // B*S = 2,097,152

    const int block = 256;
    const int grid = (npts + block - 1) / block;  // 8192 blocks, 1 pt/thread

    QuantumKernelEmbedding_kernel<<<grid, block, 0, stream>>>(x, refs, out, npts);
}